// Round 6
// baseline (385.789 us; speedup 1.0000x reference)
//
#include <hip/hip_runtime.h>

// Grouped GRU: G=64, D=16, H=8, B=64, T=512. R13: 8 lanes/cell + 2 waves/SIMD.
//
// Evidence through R11: wall-step is ~590-650 cyc across FOUR structures with
// per-step instruction counts 118/134/65 => neither pure-issue nor pure-chain;
// books balance with real costs: pk_fma_f32=4cyc (no throughput win vs scalar),
// trans=16cyc wave64 on a separate pipe (excluded from VALUBusy: R8 206/590=35%,
// R11 342/600=57%, both match per-active-SIMD busy), DPP has hazard nops.
// Split-K (R11) DUPLICATED trans/DPP per cell -> more issue per cell; s=8 is
// issue-optimal (one trans instr serves 8 cells; VALU ~210 cyc/step/wave).
// Remaining ~380 cyc/step is chain stall a lone wave can't fill, and
// waves_per_eu(1,1) forbade a partner all session.
// R13: stack 2 waves/SIMD: 512-thread blocks (8 waves/wg = 2/SIMD round-robin)
// x 64 blocks; demand 2x210=420 < 590 -> wall-step ~420-500.
// VGPR must be <=128: R10 body (per-lane 8B x pairs, ring=16 VGPR) with gx
// ring cut 4->2 slots (step reads BEFORE proj refills same slot) ~= 123 VGPR.
// waves_per_eu(2,2) forces the allocator to the 128 cap.
// Predicted: VGPR<=128, dur 128 -> 90-110us, VALUBusy 57 -> 75-100%,
// Occupancy ~5-6% (8/CU on 64 CUs), FETCH ~65MB unchanged (watch for spill
// inflation), absmax 0.00390625 unchanged.
//
// Carried: DPP x-gather proj w/ jmap-permuted wih (R10); gate scales
// pre-folded (-log2e r,z; +2log2e n); b_hh_n inside r*(...) (R7); 8-deep
// per-lane x ring, proj 2 steps ahead, single ring pin per body.

#define Gn 64
#define Dn 16
#define Hn 8
#define Tn 512

typedef float v2f __attribute__((ext_vector_type(2)));

__device__ __forceinline__ float rcp_fast(float v) { return __builtin_amdgcn_rcpf(v); }
__device__ __forceinline__ float exp2_fast(float v) { return __builtin_amdgcn_exp2f(v); }

#define KNL (-1.44269504088896340736f)   // -log2(e)
#define KP2 ( 2.88539008177792681472f)   // +2*log2(e)

template <int CTRL>
__device__ __forceinline__ float dppf(float v) {
    return __int_as_float(
        __builtin_amdgcn_update_dpp(0, __float_as_int(v), CTRL, 0xF, 0xF, false));
}
template <int CTRL>
__device__ __forceinline__ v2f dpp2(v2f v) {
    v2f r;
    r.x = dppf<CTRL>(v.x);
    r.y = dppf<CTRL>(v.y);
    return r;
}

__global__ __attribute__((amdgpu_flat_work_group_size(512, 512),
                          amdgpu_waves_per_eu(2, 2)))
void mcgru_kernel(
    const float* __restrict__ x,     // [B, T, G*D]
    const float* __restrict__ W_ih,  // [G, 3H, D]
    const float* __restrict__ W_hh,  // [G, 3H, H]
    const float* __restrict__ b_ih,  // [G, 3H]
    const float* __restrict__ b_hh,  // [G, 3H]
    float* __restrict__ out)         // [B, T, G, H]
{
    const int tid  = blockIdx.x * blockDim.x + threadIdx.x;
    const int cell = tid >> 3;           // 8 lanes per cell
    const int l    = tid & 7;            // lane within cell (octet-local)
    const int g    = cell & (Gn - 1);
    const int b    = cell >> 6;
    const int s4   = l & 3;
    const int q    = l >> 2;

    // DPP gather order: slot k arrives from octet-lane jmap[k] = l ^ mk,
    // mk = {0,1,2,3,7,6,5,4}. Used for BOTH the h gather and the x gather.
    int jmap[8];
#pragma unroll
    for (int k = 0; k < 8; ++k) {
        const int hi2 = k >> 2, r = k & 3;
        jmap[k] = ((q ^ hi2) << 2) | (s4 ^ r ^ (hi2 ? 3 : 0));
    }

    const float scale[3] = {KNL, KNL, KP2};

    // ---- preload weights, pre-scaled, DPP-order permuted ----
    v2f   wih[3][8];    // W_ih pair k = row elems [2*jmap[k], 2*jmap[k]+1], scaled
    float whh[3][8];    // W_hh columns permuted to DPP order, scaled
    float bs[3];        // r,z: (b_ih+b_hh)*KNL ; n: b_ih*KP2 only
    float bhn;          // n-gate: b_hh * KP2, kept under the r-multiplication
#pragma unroll
    for (int qg = 0; qg < 3; ++qg) {
        const int row = qg * Hn + l;
        const float sc = scale[qg];
        const float* wr = W_ih + ((size_t)g * 24 + row) * Dn;
#pragma unroll
        for (int k = 0; k < 8; ++k) {
            const int dp = jmap[k] * 2;
            wih[qg][k] = (v2f){wr[dp] * sc, wr[dp + 1] * sc};
        }
        const float* hrow = W_hh + ((size_t)g * 24 + row) * Hn;
#pragma unroll
        for (int k = 0; k < 8; ++k) whh[qg][k] = hrow[jmap[k]] * sc;
        if (qg < 2) {
            bs[qg] = (b_ih[g * 24 + row] + b_hh[g * 24 + row]) * sc;  // additive fold OK
        } else {
            bs[qg] = b_ih[g * 24 + row] * sc;   // input-side bias only
            bhn    = b_hh[g * 24 + row] * sc;   // stays inside r*(...)
        }
    }
    // Pin weights once, pre-loop: no sink/remat into the T loop.
#pragma unroll
    for (int qg = 0; qg < 3; ++qg) {
#pragma unroll
        for (int i = 0; i < 8; ++i) asm volatile("" : "+v"(wih[qg][i]));
#pragma unroll
        for (int k = 0; k < 8; ++k) asm volatile("" : "+v"(whh[qg][k]));
        asm volatile("" : "+v"(bs[qg]));
    }
    asm volatile("" : "+v"(bhn));

    // Per-lane x pointer: this lane owns bytes [8l, 8l+8) of its cell's 64B row.
    const float* xq = x   + ((size_t)b * Tn * Gn + g) * Dn + 2 * l;
    float*       op = out + ((size_t)b * Tn * Gn + g) * Hn + l;

    auto load_x = [&](int t) -> v2f {
        return *(const v2f*)(xq + (size_t)t * (Gn * Dn));
    };
    // Gather the octet's 8 pairs via DPP, dot with permutation-folded weights.
    auto proj = [&](v2f xv, float* gx) {
        v2f X[8];
        X[0] = xv;
        X[1] = dpp2<0xB1>(xv);    // quad_perm xor1
        X[2] = dpp2<0x4E>(xv);    // quad_perm xor2
        X[3] = dpp2<0x1B>(xv);    // quad_perm xor3
        X[4] = dpp2<0x141>(X[0]); // row_half_mirror = xor7 within octet
        X[5] = dpp2<0x141>(X[1]);
        X[6] = dpp2<0x141>(X[2]);
        X[7] = dpp2<0x141>(X[3]);
#pragma unroll
        for (int qg = 0; qg < 3; ++qg) {
            v2f acc = wih[qg][0] * X[0];
#pragma unroll
            for (int i = 1; i < 8; ++i) acc += wih[qg][i] * X[i];  // v_pk_fma_f32
            gx[qg] = (bs[qg] + acc.x) + acc.y;
        }
    };

    float h = 0.0f;
    auto step = [&](const float* gx, int t) {
        float H[8];
        H[0] = h;
        H[1] = dppf<0xB1>(h);     // quad_perm xor1
        H[2] = dppf<0x4E>(h);     // quad_perm xor2
        H[3] = dppf<0x1B>(h);     // quad_perm xor3
        H[4] = dppf<0x141>(H[0]); // row_half_mirror = xor7 within octet
        H[5] = dppf<0x141>(H[1]);
        H[6] = dppf<0x141>(H[2]);
        H[7] = dppf<0x141>(H[3]);

        float gh[3];
#pragma unroll
        for (int qg = 0; qg < 3; ++qg) {
            float a = fmaf(whh[qg][1], H[1], whh[qg][0] * H[0]);
            a = fmaf(whh[qg][2], H[2], a);
            a = fmaf(whh[qg][3], H[3], a);
            // n-gate: seed with bhn so r multiplies (hn + b_hh_n), per reference
            float c = (qg == 2) ? fmaf(whh[qg][4], H[4], bhn)
                                : whh[qg][4] * H[4];
            c = fmaf(whh[qg][5], H[5], c);
            c = fmaf(whh[qg][6], H[6], c);
            c = fmaf(whh[qg][7], H[7], c);
            gh[qg] = a + c;
        }
        // weights pre-scaled: r,z rows by -log2e; n rows by +2log2e
        const float r  = rcp_fast(1.0f + exp2_fast(gx[0] + gh[0]));
        const float z  = rcp_fast(1.0f + exp2_fast(gx[1] + gh[1]));
        const float zh = z * h;
        const float om = 1.0f - z;
        const float e  = exp2_fast(fmaf(r, gh[2], gx[2]));
        const float n  = fmaf(-2.0f, rcp_fast(e + 1.0f), 1.0f);  // tanh
        h = fmaf(n, om, zh);
        __builtin_nontemporal_store(h, op + (size_t)t * (Gn * Hn));
    };

    // ---- pipeline: 8-deep ring of per-lane x pairs; proj 2 steps ahead ----
    // gx ring is 2 slots: body j -> step reads gx[j&1] FIRST, then proj
    // refills the same slot for step s+2 (register renaming handles the WAR).
    v2f   xr[8];
    float gx[2][3];
    {
        v2f t0 = load_x(0);
        v2f t1 = load_x(1);
        xr[2] = load_x(2); xr[3] = load_x(3); xr[4] = load_x(4);
        xr[5] = load_x(5); xr[6] = load_x(6); xr[7] = load_x(7);
        proj(t0, gx[0]);  // gx for step 0
        proj(t1, gx[1]);  // gx for step 1
    }

    for (int t = 0; t < Tn; t += 8) {
#pragma unroll
        for (int j = 0; j < 8; ++j) {
            const int s = t + j;
            int tl = s + 8; if (tl > Tn - 1) tl = Tn - 1;
            xr[j] = load_x(tl);           // x for step s+8, in flight 6 bodies
            // pin slot (j+2)&7 (loaded 6 bodies ago -> vmcnt wait is free);
            // blocks remat/sink of the consumed slot.
            asm volatile("" : "+v"(xr[(j + 2) & 7]));
            step(gx[j & 1], s);           // recurrent chain for step s
            proj(xr[(j + 2) & 7], gx[j & 1]);  // gx for step s+2 (slot reuse)
        }
    }
}

extern "C" void kernel_launch(void* const* d_in, const int* in_sizes, int n_in,
                              void* d_out, int out_size, void* d_ws, size_t ws_size,
                              hipStream_t stream) {
    const float* x    = (const float*)d_in[0];
    const float* W_ih = (const float*)d_in[1];
    const float* W_hh = (const float*)d_in[2];
    const float* b_ih = (const float*)d_in[3];
    const float* b_hh = (const float*)d_in[4];
    float* out = (float*)d_out;

    // 4096 cells * 8 lanes = 32768 threads = 512 waves.
    // 512-thread blocks: 8 waves/workgroup -> exactly 2 waves/SIMD on a CU;
    // 64 blocks over 256 CUs (1 block/CU on 64 CUs).
    dim3 grid(64), block(512);
    hipLaunchKernelGGL(mcgru_kernel, grid, block, 0, stream,
                       x, W_ih, W_hh, b_ih, b_hh, out);
}

// Round 10
// 268.381 us; speedup vs baseline: 1.4375x; 1.4375x over previous
//
#include <hip/hip_runtime.h>

// Grouped GRU: G=64, D=16, H=8, B=64, T=512.
// R17 = R15/R16 resubmitted verbatim (rounds 7-9: three straight GPU
// acquisition failures; the producer/consumer design has never executed).
// Audits across the waits: barrier counts matched (65/65), buffer intervals
// disjoint, rule-#20 clean (named xrA/xrB after x2 unroll), LDS=12288B,
// conflict-free LDS addressing, wave-uniform branch barriers legal.
//
// R15 = R14 (producer/consumer wave split) + rule-#20 fix: the producer's
// 2-chunk x ring was xr[2][CHUNK] indexed by runtime k&1 -> scratch demotion
// (runtime-indexed ext_vector arrays go to localMem). Producer main loop is
// unrolled x2 with NAMED buffers xrA/xrB so all register indices are
// compile-time constant.
//
// Evidence: R13 (2 waves/SIMD) = 2x single-wave time => per-wave stream is
// issue-bound (~70-85% of its SIMD's issue port; VALUBusy normalizes over ALL
// SIMDs: R8 35%x2=70%, R10 36%x2=72%, R13 21%x4=84%). ~150 cyc/step stall is
// chain latency. Only lever left: REMOVE instructions from the serial wave.
// The x-projection (~150-160 issue cyc/step) has no dependence on h.
// Design: block=128 = consumer wave (recurrence only: 3 ds_reads + h-gather
// + gh + gates + store) + producer wave (x loads + DPP gather + pk_fma proj,
// 1 chunk=8 steps ahead) over a 2-chunk LDS ring (12.3 KB). Sync = raw
// s_barrier + lgkmcnt(0) ONLY — __syncthreads' vmcnt(0) drain would stall
// the producer's x prefetch ring. Producer x ring is 2 chunks deep (loads
// issued ~1 full iteration (~2600 cyc) before use > ~900 cyc HBM latency).
// 512 blocks x 2 waves = 1024 waves = 1/SIMD everywhere; waves_per_eu(1,1)
// forbids 2/SIMD stacking (R13 regression).
// Predicted: dispatch 126 -> 55-85 us, VALUBusy 55-80%, LDS 12288,
// VGPR ~120-150 (no scratch: FETCH must stay ~65.7MB), absmax unchanged,
// SQ_LDS_BANK_CONFLICT ~0.
//
// Carried (validated): consumer step = R7 verbatim (b_hh_n inside r*(...));
// producer proj = R10's per-lane-pair + jmap-folded wih; gate scales
// pre-folded (-log2e r,z; +2log2e n); exp2/rcp gates.

#define Gn 64
#define Dn 16
#define Hn 8
#define Tn 512
#define CHUNK 8
#define NCH (Tn / CHUNK)   // 64 chunks (even, so the x2-unrolled loop is exact)

typedef float v2f __attribute__((ext_vector_type(2)));

__device__ __forceinline__ float rcp_fast(float v) { return __builtin_amdgcn_rcpf(v); }
__device__ __forceinline__ float exp2_fast(float v) { return __builtin_amdgcn_exp2f(v); }

#define KNL (-1.44269504088896340736f)   // -log2(e)
#define KP2 ( 2.88539008177792681472f)   // +2*log2(e)

template <int CTRL>
__device__ __forceinline__ float dppf(float v) {
    return __int_as_float(
        __builtin_amdgcn_update_dpp(0, __float_as_int(v), CTRL, 0xF, 0xF, false));
}
template <int CTRL>
__device__ __forceinline__ v2f dpp2(v2f v) {
    v2f r;
    r.x = dppf<CTRL>(v.x);
    r.y = dppf<CTRL>(v.y);
    return r;
}

// Barrier WITHOUT vmcnt drain: LDS visibility needs lgkmcnt(0) only.
__device__ __forceinline__ void sync_lds() {
    asm volatile("s_waitcnt lgkmcnt(0)" ::: "memory");
    __builtin_amdgcn_s_barrier();
}

__global__ __attribute__((amdgpu_flat_work_group_size(128, 128),
                          amdgpu_waves_per_eu(1, 1)))
void mcgru_kernel(
    const float* __restrict__ x,     // [B, T, G*D]
    const float* __restrict__ W_ih,  // [G, 3H, D]
    const float* __restrict__ W_hh,  // [G, 3H, H]
    const float* __restrict__ b_ih,  // [G, 3H]
    const float* __restrict__ b_hh,  // [G, 3H]
    float* __restrict__ out)         // [B, T, G, H]
{
    // gx ring: [buffer][step-in-chunk][gate][consumer-lane]; chunk c -> buf c&1
    __shared__ float gxs[2][CHUNK][3][64];

    const int tlane = threadIdx.x & 63;
    const int wid   = threadIdx.x >> 6;      // 0 = consumer, 1 = producer
    const int c     = tlane >> 3;            // cell slot within block (0..7)
    const int u     = tlane & 7;             // hidden unit / octet lane
    const int cell  = blockIdx.x * 8 + c;
    const int g     = cell & (Gn - 1);
    const int b     = cell >> 6;
    const int s4 = u & 3, q = u >> 2;

    // DPP gather order within an aligned octet: slot k arrives from lane
    // u ^ mk, mk = {0,1,2,3,7,6,5,4}.
    int jmap[8];
#pragma unroll
    for (int k = 0; k < 8; ++k) {
        const int hi2 = k >> 2, r = k & 3;
        jmap[k] = ((q ^ hi2) << 2) | (s4 ^ r ^ (hi2 ? 3 : 0));
    }
    const float scale[3] = {KNL, KNL, KP2};

    if (wid == 1) {
        // ---------------- producer wave: gx projections ----------------
        v2f wih[3][8];   // pair k = x-row elems [2*jmap[k], 2*jmap[k]+1], scaled
        float bs[3];     // r,z: (b_ih+b_hh)*KNL ; n: b_ih*KP2 only
#pragma unroll
        for (int qg = 0; qg < 3; ++qg) {
            const int row = qg * Hn + u;
            const float sc = scale[qg];
            const float* wr = W_ih + ((size_t)g * 24 + row) * Dn;
#pragma unroll
            for (int k = 0; k < 8; ++k) {
                const int dp = jmap[k] * 2;
                wih[qg][k] = (v2f){wr[dp] * sc, wr[dp + 1] * sc};
            }
            bs[qg] = (qg < 2)
                ? (b_ih[g * 24 + row] + b_hh[g * 24 + row]) * sc
                : b_ih[g * 24 + row] * sc;   // n: input-side bias only
        }
#pragma unroll
        for (int qg = 0; qg < 3; ++qg) {
#pragma unroll
            for (int i = 0; i < 8; ++i) asm volatile("" : "+v"(wih[qg][i]));
            asm volatile("" : "+v"(bs[qg]));
        }

        // Per-lane x pair: lane (c,u) owns elems [2u, 2u+2) of cell c's row.
        const float* xq = x + ((size_t)b * Tn * Gn + g) * Dn + 2 * u;
        auto load_x = [&](int t) -> v2f {
            return *(const v2f*)(xq + (size_t)t * (Gn * Dn));
        };
        auto proj_store = [&](v2f xv, float* dst) {
            v2f X[8];
            X[0] = xv;
            X[1] = dpp2<0xB1>(xv);    // quad_perm xor1
            X[2] = dpp2<0x4E>(xv);    // quad_perm xor2
            X[3] = dpp2<0x1B>(xv);    // quad_perm xor3
            X[4] = dpp2<0x141>(X[0]); // row_half_mirror = xor7 within octet
            X[5] = dpp2<0x141>(X[1]);
            X[6] = dpp2<0x141>(X[2]);
            X[7] = dpp2<0x141>(X[3]);
#pragma unroll
            for (int qg = 0; qg < 3; ++qg) {
                v2f acc = wih[qg][0] * X[0];
#pragma unroll
                for (int i = 1; i < 8; ++i) acc += wih[qg][i] * X[i];  // pk_fma
                dst[qg * 64] = (bs[qg] + acc.x) + acc.y;               // ds_write
            }
        };

        // 2-chunk-deep x ring, NAMED buffers (rule #20: no runtime reg index):
        // xrA holds even chunks, xrB holds odd chunks.
        v2f xrA[CHUNK], xrB[CHUNK];
#pragma unroll
        for (int j = 0; j < CHUNK; ++j) xrA[j] = load_x(j);           // chunk 0
#pragma unroll
        for (int j = 0; j < CHUNK; ++j) xrB[j] = load_x(CHUNK + j);   // chunk 1
#pragma unroll
        for (int j = 0; j < CHUNK; ++j)
            proj_store(xrA[j], &gxs[0][j][0][tlane]);
        sync_lds();   // chunk 0 ready

        // x2-unrolled main loop: even sub-iter produces odd chunk from xrB,
        // reloads xrA; odd sub-iter produces even chunk from xrA, reloads xrB.
        for (int k = 0; k < NCH; k += 2) {
            // ---- sub-iteration k (even): consumer eats chunk k ----
            if (k + 1 < NCH) {
#pragma unroll
                for (int j = 0; j < CHUNK; ++j)
                    proj_store(xrB[j], &gxs[1][j][0][tlane]);  // chunk k+1 (odd)
            }
            if (k + 2 < NCH) {
#pragma unroll
                for (int j = 0; j < CHUNK; ++j)
                    xrA[j] = load_x((k + 2) * CHUNK + j);      // chunk k+2
            }
            sync_lds();
            // ---- sub-iteration k+1 (odd): consumer eats chunk k+1 ----
            if (k + 2 < NCH) {
#pragma unroll
                for (int j = 0; j < CHUNK; ++j)
                    proj_store(xrA[j], &gxs[0][j][0][tlane]);  // chunk k+2 (even)
            }
            if (k + 3 < NCH) {
#pragma unroll
                for (int j = 0; j < CHUNK; ++j)
                    xrB[j] = load_x((k + 3) * CHUNK + j);      // chunk k+3
            }
            sync_lds();
        }
    } else {
        // ---------------- consumer wave: the recurrence ----------------
        float whh[3][8], bhn;
#pragma unroll
        for (int qg = 0; qg < 3; ++qg) {
            const int row = qg * Hn + u;
            const float sc = scale[qg];
            const float* hrow = W_hh + ((size_t)g * 24 + row) * Hn;
#pragma unroll
            for (int k = 0; k < 8; ++k) whh[qg][k] = hrow[jmap[k]] * sc;
        }
        bhn = b_hh[g * 24 + 2 * Hn + u] * KP2;   // stays inside r*(...)
#pragma unroll
        for (int qg = 0; qg < 3; ++qg)
#pragma unroll
            for (int k = 0; k < 8; ++k) asm volatile("" : "+v"(whh[qg][k]));
        asm volatile("" : "+v"(bhn));

        float* op = out + ((size_t)b * Tn * Gn + g) * Hn + u;
        float h = 0.0f;
        sync_lds();   // wait for chunk 0

        for (int k = 0; k < NCH; ++k) {
            // LDS addressing with runtime k&1 is fine (memory, not registers)
            const float* bufp = &gxs[k & 1][0][0][tlane];
#pragma unroll
            for (int j = 0; j < CHUNK; ++j) {
                const float gx0 = bufp[(j * 3 + 0) * 64];   // ds_read, lane-linear
                const float gx1 = bufp[(j * 3 + 1) * 64];
                const float gx2 = bufp[(j * 3 + 2) * 64];

                float H[8];
                H[0] = h;
                H[1] = dppf<0xB1>(h);     // quad_perm xor1
                H[2] = dppf<0x4E>(h);     // quad_perm xor2
                H[3] = dppf<0x1B>(h);     // quad_perm xor3
                H[4] = dppf<0x141>(H[0]); // half-mirror = xor7 within octet
                H[5] = dppf<0x141>(H[1]);
                H[6] = dppf<0x141>(H[2]);
                H[7] = dppf<0x141>(H[3]);

                float gh[3];
#pragma unroll
                for (int qg = 0; qg < 3; ++qg) {
                    float a = fmaf(whh[qg][1], H[1], whh[qg][0] * H[0]);
                    a = fmaf(whh[qg][2], H[2], a);
                    a = fmaf(whh[qg][3], H[3], a);
                    // n-gate: seed with bhn so r multiplies (hn + b_hh_n)
                    float cc = (qg == 2) ? fmaf(whh[qg][4], H[4], bhn)
                                         : whh[qg][4] * H[4];
                    cc = fmaf(whh[qg][5], H[5], cc);
                    cc = fmaf(whh[qg][6], H[6], cc);
                    cc = fmaf(whh[qg][7], H[7], cc);
                    gh[qg] = a + cc;
                }
                // weights pre-scaled: r,z by -log2e; n by +2log2e
                const float r  = rcp_fast(1.0f + exp2_fast(gx0 + gh[0]));
                const float z  = rcp_fast(1.0f + exp2_fast(gx1 + gh[1]));
                const float zh = z * h;
                const float om = 1.0f - z;
                const float e  = exp2_fast(fmaf(r, gh[2], gx2));
                const float n  = fmaf(-2.0f, rcp_fast(e + 1.0f), 1.0f);  // tanh
                h = fmaf(n, om, zh);
                __builtin_nontemporal_store(
                    h, op + (size_t)(k * CHUNK + j) * (Gn * Hn));
            }
            sync_lds();   // release this buffer / wait for next chunk
        }
    }
}

extern "C" void kernel_launch(void* const* d_in, const int* in_sizes, int n_in,
                              void* d_out, int out_size, void* d_ws, size_t ws_size,
                              hipStream_t stream) {
    const float* x    = (const float*)d_in[0];
    const float* W_ih = (const float*)d_in[1];
    const float* W_hh = (const float*)d_in[2];
    const float* b_ih = (const float*)d_in[3];
    const float* b_hh = (const float*)d_in[4];
    float* out = (float*)d_out;

    // 4096 cells / 8 cells-per-block = 512 blocks x 128 threads
    // = 1024 waves over 1024 SIMDs: 1 wave/SIMD everywhere.
    dim3 grid(512), block(128);
    hipLaunchKernelGGL(mcgru_kernel, grid, block, 0, stream,
                       x, W_ih, W_hh, b_ih, b_hh, out);
}